// Round 3
// baseline (1446.735 us; speedup 1.0000x reference)
//
#include <hip/hip_runtime.h>
#include <hip/hip_bf16.h>

// Problem constants (MoCo): b=256, nc=5 -> M=1280 rows
#define M_     1280
#define DIM    128
#define DMLP   2048
#define KQ     65536
#define NCOLS  65537ull   // 1 + KQ logits columns
#define NTOPK  5
#define NCHUNK 256        // KQ / 256 (one chunk per gemm2 N-tile)
#define NBLK1  512        // KQ / 128 (gemm1 N-tiles, lse partials)
#define NTK    32         // DMLP / 64 K-tiles for gemm2
#define INV_T  14.285714285714286f   // 1/0.07

typedef __attribute__((ext_vector_type(8))) short bf16x8;  // 8 bf16 (4 VGPRs)
typedef __attribute__((ext_vector_type(4))) float f32x4;   // MFMA accum

static __device__ __forceinline__ unsigned short f2bf(float x){
  union { __hip_bfloat16 h; unsigned short u; } cv;
  cv.h = __float2bfloat16(x);
  return cv.u;
}

// async global->LDS, 16B per lane (m97: the 1.69x step)
#define GLDS16(gp, lp) __builtin_amdgcn_global_load_lds( \
    (const __attribute__((address_space(1))) void*)(gp), \
    (__attribute__((address_space(3))) void*)(lp), 16, 0, 0)

#define BAR()   asm volatile("s_barrier" ::: "memory")
#define VMW(n)  asm volatile("s_waitcnt vmcnt(" #n ")" ::: "memory")

// ---------- transpose + fp32->bf16 convert: in [R][C] f32 -> out [C][R] bf16
__global__ __launch_bounds__(256) void transpose_bf16(
    const float* __restrict__ in, unsigned short* __restrict__ out, int R, int C){
  __shared__ float tile[64][65];             // +1 pad: no bank conflicts
  const int c0 = blockIdx.x * 64, r0 = blockIdx.y * 64;
  const int t = threadIdx.x;
  #pragma unroll
  for (int i = 0; i < 4; ++i){
    int lin = t + i * 256;                   // 0..1023, one float4 each
    int rr = lin >> 4;
    int cc = (lin & 15) * 4;
    const float4 v = *(const float4*)(in + (size_t)(r0 + rr) * C + c0 + cc);
    tile[rr][cc + 0] = v.x; tile[rr][cc + 1] = v.y;
    tile[rr][cc + 2] = v.z; tile[rr][cc + 3] = v.w;
  }
  __syncthreads();
  #pragma unroll
  for (int i = 0; i < 4; ++i){
    int lin = t + i * 256;
    int oc  = lin >> 4;                      // out row (original col)
    int orr = (lin & 15) * 4;                // out col group (original rows)
    ushort4 u;
    u.x = f2bf(tile[orr + 0][oc]); u.y = f2bf(tile[orr + 1][oc]);
    u.z = f2bf(tile[orr + 2][oc]); u.w = f2bf(tile[orr + 3][oc]);
    *(ushort4*)(out + (size_t)(c0 + oc) * R + r0 + orr) = u;
  }
}

// ---------- normalize q rows -> bf16 qn; also write l_pos (logits col 0)
__global__ __launch_bounds__(128) void normq_kernel(
    const float* __restrict__ q, const float* __restrict__ k,
    unsigned short* __restrict__ qn, float* __restrict__ outp){
  const int i = blockIdx.x;                  // 0..1279
  const int t = threadIdx.x;                 // 0..127
  const float qv = q[(size_t)i * DIM + t];
  const float kv = k[(size_t)(i / 5) * DIM + t];
  float a = qv * qv, b = kv * kv, d = qv * kv;
  #pragma unroll
  for (int s = 32; s >= 1; s >>= 1){
    a += __shfl_down(a, s, 64);
    b += __shfl_down(b, s, 64);
    d += __shfl_down(d, s, 64);
  }
  __shared__ float red[6];
  if ((t & 63) == 0){ red[(t >> 6) * 3 + 0] = a; red[(t >> 6) * 3 + 1] = b; red[(t >> 6) * 3 + 2] = d; }
  __syncthreads();
  const float qq = red[0] + red[3], kk = red[1] + red[4], qk = red[2] + red[5];
  const float qnorm = fmaxf(sqrtf(qq), 1e-12f);
  qn[(size_t)i * DIM + t] = f2bf(qv / qnorm);
  if (t == 0){
    const float knorm = fmaxf(sqrtf(kk), 1e-12f);
    outp[(size_t)i * NCOLS] = (qk / (qnorm * knorm)) * INV_T;   // l_pos / T
  }
}

// ---------- normalize q_backbone rows -> bf16
__global__ __launch_bounds__(256) void normqb_kernel(
    const float* __restrict__ qb, unsigned short* __restrict__ out){
  const int i = blockIdx.x, t = threadIdx.x;
  const float* p = qb + (size_t)i * DMLP;
  float x[8]; float ss = 0.f;
  #pragma unroll
  for (int j = 0; j < 8; ++j){ x[j] = p[t + j * 256]; ss += x[j] * x[j]; }
  #pragma unroll
  for (int s = 32; s >= 1; s >>= 1) ss += __shfl_down(ss, s, 64);
  __shared__ float r4[4];
  if ((t & 63) == 0) r4[t >> 6] = ss;
  __syncthreads();
  const float tot = r4[0] + r4[1] + r4[2] + r4[3];
  const float inv = 1.0f / fmaxf(sqrtf(tot), 1e-12f);
  unsigned short* o = out + (size_t)i * DMLP;
  #pragma unroll
  for (int j = 0; j < 8; ++j) o[t + j * 256] = f2bf(x[j] * inv);
}

// ---------- top-5 insertion (sorted desc; strict > keeps earliest index on ties)
static __device__ __forceinline__ void tk_insert(float* v, int* ix, float nv, int ni){
  if (nv > v[4]){
    v[4] = nv; ix[4] = ni;
    #pragma unroll
    for (int j = 4; j > 0; --j){
      if (v[j] > v[j - 1]){
        float tv = v[j]; v[j] = v[j - 1]; v[j - 1] = tv;
        int   ti = ix[j]; ix[j] = ix[j - 1]; ix[j - 1] = ti;
      }
    }
  }
}

// ---------- GEMM1 (logits): m97-structure 128x128 tile, BK=32, KD=128.
// Writes logits*INV_T, plus per-(row, 128-col-tile) lse partials (max, sumexp).
__global__ __launch_bounds__(256) void gemm1_mfma(
    const unsigned short* __restrict__ A, const unsigned short* __restrict__ BT,
    float* __restrict__ outp, float* __restrict__ pm, float* __restrict__ ps){
  __shared__ __attribute__((aligned(16))) unsigned char smem[16512];
  unsigned short* At = (unsigned short*)smem;
  unsigned short* Bt = At + 128 * 32;

  const int t    = threadIdx.x;
  const int lane = t & 63;
  const int wv   = t >> 6;        // wave 0..3, owns 32 rows x 128 cols
  const int lid  = lane & 15;
  const int quad = lane >> 4;
  const int m0 = blockIdx.x * 128;
  const int n0 = blockIdx.y * 128;

  f32x4 acc[2][8];
  #pragma unroll
  for (int mt = 0; mt < 2; ++mt)
    #pragma unroll
    for (int nt = 0; nt < 8; ++nt)
      acc[mt][nt] = f32x4{0.f, 0.f, 0.f, 0.f};

  const int arow = t >> 2;              // staging row (4 lanes x 16B = 64B/row)
  const int ace  = (t & 3) * 8;         // staging col (elements)

  for (int kt = 0; kt < DIM; kt += 32){
    if (kt) __syncthreads();
    #pragma unroll
    for (int it = 0; it < 2; ++it){
      int row = arow + it * 64;
      GLDS16(A  + (size_t)(m0 + row) * DIM + kt + ace, At + (t + it * 256) * 8);
    }
    #pragma unroll
    for (int it = 0; it < 2; ++it){
      int row = arow + it * 64;
      GLDS16(BT + (size_t)(n0 + row) * DIM + kt + ace, Bt + (t + it * 256) * 8);
    }
    asm volatile("s_waitcnt vmcnt(0)" ::: "memory");
    __syncthreads();

    bf16x8 af[2], bfr[8];
    #pragma unroll
    for (int mt = 0; mt < 2; ++mt)
      af[mt] = *(const bf16x8*)(At + (wv * 32 + mt * 16 + lid) * 32 + quad * 8);
    #pragma unroll
    for (int nt = 0; nt < 8; ++nt)
      bfr[nt] = *(const bf16x8*)(Bt + (nt * 16 + lid) * 32 + quad * 8);
    #pragma unroll
    for (int mt = 0; mt < 2; ++mt)
      #pragma unroll
      for (int nt = 0; nt < 8; ++nt)
        acc[mt][nt] = __builtin_amdgcn_mfma_f32_16x16x32_bf16(af[mt], bfr[nt], acc[mt][nt], 0, 0, 0);
  }

  // C/D layout (m89-verified): col = lane&15, row = quad*4 + reg
  float mx[2][4], sm[2][4];
  #pragma unroll
  for (int mt = 0; mt < 2; ++mt)
    #pragma unroll
    for (int r = 0; r < 4; ++r) mx[mt][r] = -3.0e38f;
  #pragma unroll
  for (int mt = 0; mt < 2; ++mt)
    #pragma unroll
    for (int nt = 0; nt < 8; ++nt)
      #pragma unroll
      for (int r = 0; r < 4; ++r){
        const int mg = m0 + wv * 32 + mt * 16 + quad * 4 + r;
        const int ng = n0 + nt * 16 + lid;
        const float x = acc[mt][nt][r] * INV_T;
        outp[(size_t)mg * NCOLS + 1 + ng] = x;
        mx[mt][r] = fmaxf(mx[mt][r], x);
      }
  // 16-lane (lid) reduction: each quad owns its own 4 rows per mt
  #pragma unroll
  for (int mt = 0; mt < 2; ++mt)
    #pragma unroll
    for (int r = 0; r < 4; ++r){
      #pragma unroll
      for (int s = 8; s >= 1; s >>= 1)
        mx[mt][r] = fmaxf(mx[mt][r], __shfl_xor(mx[mt][r], s, 64));
      sm[mt][r] = 0.f;
    }
  #pragma unroll
  for (int mt = 0; mt < 2; ++mt)
    #pragma unroll
    for (int nt = 0; nt < 8; ++nt)
      #pragma unroll
      for (int r = 0; r < 4; ++r)
        sm[mt][r] += __expf(acc[mt][nt][r] * INV_T - mx[mt][r]);
  #pragma unroll
  for (int mt = 0; mt < 2; ++mt)
    #pragma unroll
    for (int r = 0; r < 4; ++r){
      #pragma unroll
      for (int s = 8; s >= 1; s >>= 1)
        sm[mt][r] += __shfl_xor(sm[mt][r], s, 64);
      if (lid == 0){
        const int mg = m0 + wv * 32 + mt * 16 + quad * 4 + r;
        pm[(size_t)mg * NBLK1 + blockIdx.y] = mx[mt][r];
        ps[(size_t)mg * NBLK1 + blockIdx.y] = sm[mt][r];
      }
    }
}

// ================== GEMM2: 256x256 tile, BK=64, 8 waves, 4-phase DEEP pipeline.
// Every stage is issued 4-5 phases before its vmcnt wait (12 loads in flight =
// 1.5 K-tiles), so the counted VMW at each phase HEAD is normally a no-op and
// waves never stall in lockstep on HBM latency. VMW precedes the barrier, so
// all waves' loads are drained before ANY wave's ds_read (race-proof).
// (T1 XCD-chunk + T2 granule-XOR swizzle + T3/T4 deep counted vmcnt + T5 setprio)

static __device__ __forceinline__ void stage_half_g2(
    const unsigned short* __restrict__ G, int growbase, int kt,
    unsigned short* dst, int t){
  // half-tile: 128 rows x 64 cols bf16 = 1024 x 16B granules; LDS dest linear,
  // global source pre-swizzled with g' = g ^ (row&7) (rule #21: both-sides).
  #pragma unroll
  for (int l = 0; l < 2; ++l){
    const int p = l * 512 + t;         // granule index; per-wave base uniform
    const int r = p >> 3;              // row within half
    const int g = (p & 7) ^ (r & 7);   // swizzled source granule
    GLDS16(G + (size_t)(growbase + r) * DMLP + kt * 64 + g * 8, dst + p * 8);
  }
}

#define RDA(mi_, SRC) do { _Pragma("unroll") for (int mf = 0; mf < 4; ++mf){ \
    const int R_ = (mi_) * 128 + wm * 64 + mf * 16 + lid; \
    av[mi_][mf][0] = *(const bf16x8*)((SRC) + R_ * 64 + sw0); \
    av[mi_][mf][1] = *(const bf16x8*)((SRC) + R_ * 64 + sw1); } } while(0)

#define RDB(nj_, SRC) do { _Pragma("unroll") for (int nf = 0; nf < 2; ++nf){ \
    const int S_ = (nj_) * 128 + wn * 32 + nf * 16 + lid; \
    bv[nf][0] = *(const bf16x8*)((SRC) + S_ * 64 + sw0); \
    bv[nf][1] = *(const bf16x8*)((SRC) + S_ * 64 + sw1); } } while(0)

#define MMQ(mi_, nj_) do { __builtin_amdgcn_s_setprio(1); \
    _Pragma("unroll") for (int mf = 0; mf < 4; ++mf) \
    _Pragma("unroll") for (int nf = 0; nf < 2; ++nf){ \
      acc[mi_][nj_][mf][nf] = __builtin_amdgcn_mfma_f32_16x16x32_bf16(av[mi_][mf][0], bv[nf][0], acc[mi_][nj_][mf][nf], 0, 0, 0); \
      acc[mi_][nj_][mf][nf] = __builtin_amdgcn_mfma_f32_16x16x32_bf16(av[mi_][mf][1], bv[nf][1], acc[mi_][nj_][mf][nf], 0, 0, 0); } \
    __builtin_amdgcn_s_setprio(0); } while(0)

__global__ __launch_bounds__(512, 2) void gemm2_topk(
    const unsigned short* __restrict__ A, const unsigned short* __restrict__ BT,
    float* __restrict__ cval, int* __restrict__ cidx){
  // [buf][0=A,1=B][256 rows x 64 cols] bf16 = 128 KB total
  __shared__ __attribute__((aligned(16))) unsigned short lds[2][2][256 * 64];

  const int t    = threadIdx.x;           // 0..511
  const int lane = t & 63;
  const int wv   = t >> 6;                // wave 0..7
  const int wm   = wv >> 2;               // 0..1 (M within quadrant)
  const int wn   = wv & 3;                // 0..3 (N within quadrant)
  const int lid  = lane & 15;
  const int quad = lane >> 4;
  const int l7   = lid & 7;
  const int sw0  = ((quad    ) ^ l7) * 8; // swizzled granule offset, ks=0
  const int sw1  = ((quad ^ 4) ^ l7) * 8; // ks=1

  // T1: bijective XCD-chunked remap (1280 % 8 == 0): XCD x gets 32 consecutive
  // N-tiles x all 5 M-tiles -> the 5 sharers of each 1MB B-slab are co-resident.
  const int h  = blockIdx.x;
  const int wg = (h & 7) * 160 + (h >> 3);
  const int bm = wg % 5;
  const int bn = wg / 5;
  const int m0 = bm * 256;
  const int n0 = bn * 256;

  f32x4 acc[2][2][4][2];
  #pragma unroll
  for (int a = 0; a < 2; ++a)
    #pragma unroll
    for (int b = 0; b < 2; ++b)
      #pragma unroll
      for (int c = 0; c < 4; ++c)
        #pragma unroll
        for (int d = 0; d < 2; ++d)
          acc[a][b][c][d] = f32x4{0.f, 0.f, 0.f, 0.f};

  bf16x8 av[2][4][2];   // both A sets live across each kt
  bf16x8 bv[2][2];      // single B set, rotated in place (B-seq 0,0,1,1)

  // prologue: issue order matches steady-state vmcnt accounting:
  // A0(0),B0(0),A1(0),B1(0),A0(1),B0(1) = 12 loads in flight
  stage_half_g2(A,  m0,       0, &lds[0][0][0],        t);
  stage_half_g2(BT, n0,       0, &lds[0][1][0],        t);
  stage_half_g2(A,  m0 + 128, 0, &lds[0][0][128 * 64], t);
  stage_half_g2(BT, n0 + 128, 0, &lds[0][1][128 * 64], t);
  stage_half_g2(A,  m0,       1, &lds[1][0][0],        t);
  stage_half_g2(BT, n0,       1, &lds[1][1][0],        t);
  VMW(8);               // A0(0),B0(0) landed (oldest 4 of 12)
  BAR();
  RDA(0, &lds[0][0][0]);          // av[0] <- A0(kt0)
  RDB(0, &lds[0][1][0]);          // bv    <- B0(kt0)
  BAR();

  // steady state, per phase: {VMW(head); stage(deep); BAR; MMQ; RD(tail); BAR}
  // stage schedule: P0->A1(kt+1), P1->B1(kt+1), P2->A0(kt+2), P3->B0(kt+2)
  #pragma unroll 2
  for (int kt = 0; kt < NTK - 1; ++kt){
    unsigned short* curA = &lds[kt & 1][0][0];
    unsigned short* curB = &lds[kt & 1][1][0];
    unsigned short* nxtA = &lds[(kt + 1) & 1][0][0];
    unsigned short* nxtB = &lds[(kt + 1) & 1][1][0];
    const bool pf2 = (kt + 2 < NTK);

    // P0: need A1(kt) [issued P0(kt-1), 4 phases ago]
    VMW(6);
    stage_half_g2(A, m0 + 128, kt + 1, nxtA + 128 * 64, t);   // A1(kt+1)
    BAR();
    MMQ(0, 0);
    RDA(1, curA);                         // av[1] <- A1(kt), used P1/P2
    BAR();

    // P1: need B1(kt)
    VMW(6);
    stage_half_g2(BT, n0 + 128, kt + 1, nxtB + 128 * 64, t);  // B1(kt+1)
    BAR();
    MMQ(1, 0);
    RDB(1, curB);                         // bv <- B1(kt), used P2/P3
    BAR();

    // P2: no wait; stage A0(kt+2) into cur buf (its old contents were last
    // read at P3(kt-1), 3 barriers ago)
    if (pf2) stage_half_g2(A, m0, kt + 2, curA, t);           // A0(kt+2)
    BAR();
    MMQ(1, 1);
    BAR();

    // P3: need A0(kt+1),B0(kt+1) [issued P2/P3(kt-1)]
    if (pf2){
      VMW(6);
      stage_half_g2(BT, n0, kt + 2, curB, t);                 // B0(kt+2)
    } else {
      VMW(4);          // kt==NTK-2: A0/B0(kt+2) suppressed -> exact count
    }
    BAR();
    MMQ(0, 1);
    RDA(0, nxtA);                         // av[0] <- A0(kt+1)
    RDB(0, nxtB);                         // bv    <- B0(kt+1)
    BAR();
  }

  { // peeled kt = NTK-1: no stages, exact tail waits
    unsigned short* curA = &lds[(NTK - 1) & 1][0][0];
    unsigned short* curB = &lds[(NTK - 1) & 1][1][0];
    VMW(2);            // A1(NTK-1) landed (outstanding: A1,B1 = 4)
    BAR();
    MMQ(0, 0);
    RDA(1, curA);
    BAR();
    VMW(0);            // B1(NTK-1) landed
    BAR();
    MMQ(1, 0);
    RDB(1, curB);
    BAR();
    MMQ(1, 1);
    MMQ(0, 1);
  }

  // ---- fused top-5 over this block's 256 cols (chunk = bn) ----
  float* scratch = (float*)&lds[0][0][0];   // 128 x 133 f32 = 68 KB
  const int erow = t >> 2;     // 0..127 (row within half)
  const int eh   = t & 3;      // 4 threads/row, interleaved cols (bank-friendly)
  #pragma unroll
  for (int mi = 0; mi < 2; ++mi){
    float v[5]; int ix[5];
    #pragma unroll
    for (int j = 0; j < 5; ++j){ v[j] = -3.0e38f; ix[j] = 0; }
    #pragma unroll
    for (int nj = 0; nj < 2; ++nj){
      __syncthreads();
      #pragma unroll
      for (int mf = 0; mf < 4; ++mf)
        #pragma unroll
        for (int nf = 0; nf < 2; ++nf)
          #pragma unroll
          for (int r = 0; r < 4; ++r)
            scratch[(wm * 64 + mf * 16 + quad * 4 + r) * 133 + wn * 32 + nf * 16 + lid]
              = acc[mi][nj][mf][nf][r];
      __syncthreads();
      for (int j = 0; j < 32; ++j)
        tk_insert(v, ix, scratch[erow * 133 + j * 4 + eh], n0 + nj * 128 + j * 4 + eh);
    }
    #pragma unroll
    for (int s = 1; s <= 2; s <<= 1){      // merge the 4 per-row lists
      float pv[5]; int pi[5];
      #pragma unroll
      for (int j = 0; j < 5; ++j){ pv[j] = __shfl_xor(v[j], s, 64); pi[j] = __shfl_xor(ix[j], s, 64); }
      #pragma unroll
      for (int j = 0; j < 5; ++j) tk_insert(v, ix, pv[j], pi[j]);
    }
    if (eh == 0){
      const int rowg = m0 + mi * 128 + erow;
      const size_t cb = ((size_t)rowg * NCHUNK + bn) * NTOPK;
      #pragma unroll
      for (int j = 0; j < 5; ++j){ cval[cb + j] = v[j]; cidx[cb + j] = ix[j]; }
    }
  }
}

// ---------- merge 256 chunk top-5 lists per row -> global top-5 indices
__global__ __launch_bounds__(256) void topk_merge(
    const float* __restrict__ cval, const int* __restrict__ cidx, int* __restrict__ knn){
  const int row = blockIdx.x, t = threadIdx.x;
  float v[5]; int ix[5];
  #pragma unroll
  for (int j = 0; j < 5; ++j){ v[j] = -3.0e38f; ix[j] = 0; }
  const size_t base = (size_t)row * (NCHUNK * NTOPK);
  #pragma unroll
  for (int j = 0; j < 5; ++j){                   // 1280 candidates / 256 threads
    const int c = t * 5 + j;
    tk_insert(v, ix, cval[base + c], cidx[base + c]);
  }
  __shared__ float lv[256 * 5];
  __shared__ int   li[256 * 5];
  #pragma unroll
  for (int j = 0; j < 5; ++j){ lv[t * 5 + j] = v[j]; li[t * 5 + j] = ix[j]; }
  __syncthreads();
  if (t < 64){
    float v2[5]; int ix2[5];
    #pragma unroll
    for (int j = 0; j < 5; ++j){ v2[j] = -3.0e38f; ix2[j] = 0; }
    for (int L = 0; L < 4; ++L)
      #pragma unroll
      for (int j = 0; j < 5; ++j)
        tk_insert(v2, ix2, lv[(t * 4 + L) * 5 + j], li[(t * 4 + L) * 5 + j]);
    #pragma unroll
    for (int s = 32; s >= 1; s >>= 1){           // tree merge; lane 0 ends valid
      float pv[5]; int pi[5];
      #pragma unroll
      for (int j = 0; j < 5; ++j){ pv[j] = __shfl_down(v2[j], s, 64); pi[j] = __shfl_down(ix2[j], s, 64); }
      #pragma unroll
      for (int j = 0; j < 5; ++j) tk_insert(v2, ix2, pv[j], pi[j]);
    }
    if (t == 0){
      #pragma unroll
      for (int j = 0; j < 5; ++j) knn[(size_t)row * NTOPK + j] = ix2[j];
    }
  }
}

// ---------- merge per-tile lse partials -> per-row logsumexp
__global__ __launch_bounds__(256) void lse_merge(
    const float* __restrict__ pm, const float* __restrict__ ps,
    float* __restrict__ lse){
  const int row = blockIdx.x, t = threadIdx.x;
  const float* pmr = pm + (size_t)row * NBLK1;
  const float* psr = ps + (size_t)row * NBLK1;
  float m = -1.0e30f, s = 0.f;
  #pragma unroll
  for (int c = 0; c < 2; ++c){               // 512 partials / 256 threads
    const float om = pmr[t + c * 256], os = psr[t + c * 256];
    const float nm = fmaxf(m, om);
    s = s * __expf(m - nm) + os * __expf(om - nm);
    m = nm;
  }
  #pragma unroll
  for (int sh = 32; sh >= 1; sh >>= 1){
    const float om = __shfl_down(m, sh, 64), os = __shfl_down(s, sh, 64);
    const float nm = fmaxf(m, om);
    s = s * __expf(m - nm) + os * __expf(om - nm);
    m = nm;
  }
  __shared__ float sm2[4], ss2[4];
  if ((t & 63) == 0){ sm2[t >> 6] = m; ss2[t >> 6] = s; }
  __syncthreads();
  if (t == 0){
    float M = sm2[0], S = ss2[0];
    #pragma unroll
    for (int w = 1; w < 4; ++w){
      const float nm = fmaxf(M, sm2[w]);
      S = S * __expf(M - nm) + ss2[w] * __expf(sm2[w] - nm);
      M = nm;
    }
    lse[row] = M + __logf(S);
  }
}

// ---------- loss = mean over 6400 of (lse[row] - logit[row][1+idx])
__global__ __launch_bounds__(256) void loss_kernel(
    const float* __restrict__ logits, const float* __restrict__ lse,
    const int* __restrict__ knn, float* __restrict__ loss){
  const int i = blockIdx.x * 256 + threadIdx.x;
  float c = 0.f;
  if (i < M_){
    const float l = lse[i];
    #pragma unroll
    for (int j = 0; j < 5; ++j){
      const int id = knn[(size_t)i * NTOPK + j];
      c += l - logits[(size_t)i * NCOLS + 1 + id];
    }
    c *= (1.0f / 6400.0f);
  }
  #pragma unroll
  for (int s = 32; s >= 1; s >>= 1) c += __shfl_down(c, s, 64);
  if ((threadIdx.x & 63) == 0) atomicAdd(loss, c);
}

extern "C" void kernel_launch(void* const* d_in, const int* in_sizes, int n_in,
                              void* d_out, int out_size, void* d_ws, size_t ws_size,
                              hipStream_t stream){
  const float* q   = (const float*)d_in[0];   // [256,5,128]
  const float* k   = (const float*)d_in[1];   // [256,128]
  const float* qbI = (const float*)d_in[2];   // [256,5,2048]
  const float* que = (const float*)d_in[3];   // [128,65536]
  const float* qbb = (const float*)d_in[4];   // [2048,65536]
  float* out = (float*)d_out;

  unsigned char* w = (unsigned char*)d_ws;
  unsigned short* qn   = (unsigned short*)w; w += (size_t)M_ * DIM  * 2;   // 320 KB
  unsigned short* qbn  = (unsigned short*)w; w += (size_t)M_ * DMLP * 2;   // 5 MB
  unsigned short* queT = (unsigned short*)w; w += (size_t)KQ * DIM  * 2;   // 16 MB
  unsigned short* qbbT = (unsigned short*)w; w += (size_t)KQ * DMLP * 2;   // 256 MB
  float* cval = (float*)w;                   w += (size_t)M_ * NCHUNK * NTOPK * 4;  // 6.5 MB
  int*   cidx = (int*)w;                     w += (size_t)M_ * NCHUNK * NTOPK * 4;  // 6.5 MB
  int*   knn  = (int*)w;                     w += (size_t)M_ * NTOPK * 4;
  float* lseb = (float*)w;                   w += (size_t)M_ * 4;
  float* pm   = (float*)w;                   w += (size_t)M_ * NBLK1 * 4;  // 2.6 MB
  float* ps   = (float*)w;                   w += (size_t)M_ * NBLK1 * 4;  // 2.6 MB

  // labels (1280 int32 zeros) + loss slot, contiguous after logits
  hipMemsetAsync(out + (size_t)M_ * NCOLS, 0, (M_ + 1) * sizeof(float), stream);

  transpose_bf16<<<dim3(KQ / 64, DIM  / 64), 256, 0, stream>>>(que, queT, DIM,  KQ);
  transpose_bf16<<<dim3(KQ / 64, DMLP / 64), 256, 0, stream>>>(qbb, qbbT, DMLP, KQ);
  normq_kernel <<<M_, 128, 0, stream>>>(q, k, qn, out);
  normqb_kernel<<<M_, 256, 0, stream>>>(qbI, qbn);
  // GEMM1: x = M-tiles (fast) so the 10 blocks sharing a B tile are adjacent
  gemm1_mfma<<<dim3(10, NBLK1), 256, 0, stream>>>(qn, queT, out, pm, ps);
  // GEMM2: 256^2 4-phase deep-pipelined, 1280 blocks, XCD-chunked internally
  gemm2_topk<<<dim3(1280), 512, 0, stream>>>(qbn, qbbT, cval, cidx);
  topk_merge<<<M_, 256, 0, stream>>>(cval, cidx, knn);
  lse_merge<<<M_, 256, 0, stream>>>(pm, ps, lseb);
  loss_kernel<<<(M_ + 255) / 256, 256, 0, stream>>>(out, lseb, knn,
                                                    out + (size_t)M_ * NCOLS + M_);
}

// Round 4
// 1386.330 us; speedup vs baseline: 1.0436x; 1.0436x over previous
//
#include <hip/hip_runtime.h>
#include <hip/hip_bf16.h>

// Problem constants (MoCo): b=256, nc=5 -> M=1280 rows
#define M_     1280
#define DIM    128
#define DMLP   2048
#define KQ     65536
#define NCOLS  65537ull   // 1 + KQ logits columns
#define NTOPK  5
#define NCHUNK 256        // KQ / 256 (one chunk per gemm2 N-tile)
#define NBLK1  512        // KQ / 128 (gemm1 N-tiles, lse partials)
#define NTK    32         // DMLP / 64 K-tiles for gemm2
#define INV_T  14.285714285714286f   // 1/0.07

typedef __attribute__((ext_vector_type(8))) short bf16x8;  // 8 bf16 (4 VGPRs)
typedef __attribute__((ext_vector_type(4))) float f32x4;   // MFMA accum

static __device__ __forceinline__ unsigned short f2bf(float x){
  union { __hip_bfloat16 h; unsigned short u; } cv;
  cv.h = __float2bfloat16(x);
  return cv.u;
}

// async global->LDS, 16B per lane (m97: the 1.69x step)
#define GLDS16(gp, lp) __builtin_amdgcn_global_load_lds( \
    (const __attribute__((address_space(1))) void*)(gp), \
    (__attribute__((address_space(3))) void*)(lp), 16, 0, 0)

#define BAR()   asm volatile("s_barrier" ::: "memory")
#define VMW(n)  asm volatile("s_waitcnt vmcnt(" #n ")" ::: "memory")

// ---------- transpose + fp32->bf16 convert: in [R][C] f32 -> out [C][R] bf16
__global__ __launch_bounds__(256) void transpose_bf16(
    const float* __restrict__ in, unsigned short* __restrict__ out, int R, int C){
  __shared__ float tile[64][65];             // +1 pad: no bank conflicts
  const int c0 = blockIdx.x * 64, r0 = blockIdx.y * 64;
  const int t = threadIdx.x;
  #pragma unroll
  for (int i = 0; i < 4; ++i){
    int lin = t + i * 256;                   // 0..1023, one float4 each
    int rr = lin >> 4;
    int cc = (lin & 15) * 4;
    const float4 v = *(const float4*)(in + (size_t)(r0 + rr) * C + c0 + cc);
    tile[rr][cc + 0] = v.x; tile[rr][cc + 1] = v.y;
    tile[rr][cc + 2] = v.z; tile[rr][cc + 3] = v.w;
  }
  __syncthreads();
  #pragma unroll
  for (int i = 0; i < 4; ++i){
    int lin = t + i * 256;
    int oc  = lin >> 4;                      // out row (original col)
    int orr = (lin & 15) * 4;                // out col group (original rows)
    ushort4 u;
    u.x = f2bf(tile[orr + 0][oc]); u.y = f2bf(tile[orr + 1][oc]);
    u.z = f2bf(tile[orr + 2][oc]); u.w = f2bf(tile[orr + 3][oc]);
    *(ushort4*)(out + (size_t)(c0 + oc) * R + r0 + orr) = u;
  }
}

// ---------- normalize q rows -> bf16 qn; also write l_pos (logits col 0)
__global__ __launch_bounds__(128) void normq_kernel(
    const float* __restrict__ q, const float* __restrict__ k,
    unsigned short* __restrict__ qn, float* __restrict__ outp){
  const int i = blockIdx.x;                  // 0..1279
  const int t = threadIdx.x;                 // 0..127
  const float qv = q[(size_t)i * DIM + t];
  const float kv = k[(size_t)(i / 5) * DIM + t];
  float a = qv * qv, b = kv * kv, d = qv * kv;
  #pragma unroll
  for (int s = 32; s >= 1; s >>= 1){
    a += __shfl_down(a, s, 64);
    b += __shfl_down(b, s, 64);
    d += __shfl_down(d, s, 64);
  }
  __shared__ float red[6];
  if ((t & 63) == 0){ red[(t >> 6) * 3 + 0] = a; red[(t >> 6) * 3 + 1] = b; red[(t >> 6) * 3 + 2] = d; }
  __syncthreads();
  const float qq = red[0] + red[3], kk = red[1] + red[4], qk = red[2] + red[5];
  const float qnorm = fmaxf(sqrtf(qq), 1e-12f);
  qn[(size_t)i * DIM + t] = f2bf(qv / qnorm);
  if (t == 0){
    const float knorm = fmaxf(sqrtf(kk), 1e-12f);
    outp[(size_t)i * NCOLS] = (qk / (qnorm * knorm)) * INV_T;   // l_pos / T
  }
}

// ---------- normalize q_backbone rows -> bf16
__global__ __launch_bounds__(256) void normqb_kernel(
    const float* __restrict__ qb, unsigned short* __restrict__ out){
  const int i = blockIdx.x, t = threadIdx.x;
  const float* p = qb + (size_t)i * DMLP;
  float x[8]; float ss = 0.f;
  #pragma unroll
  for (int j = 0; j < 8; ++j){ x[j] = p[t + j * 256]; ss += x[j] * x[j]; }
  #pragma unroll
  for (int s = 32; s >= 1; s >>= 1) ss += __shfl_down(ss, s, 64);
  __shared__ float r4[4];
  if ((t & 63) == 0) r4[t >> 6] = ss;
  __syncthreads();
  const float tot = r4[0] + r4[1] + r4[2] + r4[3];
  const float inv = 1.0f / fmaxf(sqrtf(tot), 1e-12f);
  unsigned short* o = out + (size_t)i * DMLP;
  #pragma unroll
  for (int j = 0; j < 8; ++j) o[t + j * 256] = f2bf(x[j] * inv);
}

// ---------- top-5 insertion (sorted desc; strict > keeps earliest index on ties)
static __device__ __forceinline__ void tk_insert(float* v, int* ix, float nv, int ni){
  if (nv > v[4]){
    v[4] = nv; ix[4] = ni;
    #pragma unroll
    for (int j = 4; j > 0; --j){
      if (v[j] > v[j - 1]){
        float tv = v[j]; v[j] = v[j - 1]; v[j - 1] = tv;
        int   ti = ix[j]; ix[j] = ix[j - 1]; ix[j - 1] = ti;
      }
    }
  }
}

// ---------- GEMM1 (logits): m97-structure 128x128 tile, BK=32, KD=128.
// Writes logits*INV_T, plus per-(row, 128-col-tile) lse partials (max, sumexp).
__global__ __launch_bounds__(256) void gemm1_mfma(
    const unsigned short* __restrict__ A, const unsigned short* __restrict__ BT,
    float* __restrict__ outp, float* __restrict__ pm, float* __restrict__ ps){
  __shared__ __attribute__((aligned(16))) unsigned char smem[16512];
  unsigned short* At = (unsigned short*)smem;
  unsigned short* Bt = At + 128 * 32;

  const int t    = threadIdx.x;
  const int lane = t & 63;
  const int wv   = t >> 6;        // wave 0..3, owns 32 rows x 128 cols
  const int lid  = lane & 15;
  const int quad = lane >> 4;
  const int m0 = blockIdx.x * 128;
  const int n0 = blockIdx.y * 128;

  f32x4 acc[2][8];
  #pragma unroll
  for (int mt = 0; mt < 2; ++mt)
    #pragma unroll
    for (int nt = 0; nt < 8; ++nt)
      acc[mt][nt] = f32x4{0.f, 0.f, 0.f, 0.f};

  const int arow = t >> 2;              // staging row (4 lanes x 16B = 64B/row)
  const int ace  = (t & 3) * 8;         // staging col (elements)

  for (int kt = 0; kt < DIM; kt += 32){
    if (kt) __syncthreads();
    #pragma unroll
    for (int it = 0; it < 2; ++it){
      int row = arow + it * 64;
      GLDS16(A  + (size_t)(m0 + row) * DIM + kt + ace, At + (t + it * 256) * 8);
    }
    #pragma unroll
    for (int it = 0; it < 2; ++it){
      int row = arow + it * 64;
      GLDS16(BT + (size_t)(n0 + row) * DIM + kt + ace, Bt + (t + it * 256) * 8);
    }
    asm volatile("s_waitcnt vmcnt(0)" ::: "memory");
    __syncthreads();

    bf16x8 af[2], bfr[8];
    #pragma unroll
    for (int mt = 0; mt < 2; ++mt)
      af[mt] = *(const bf16x8*)(At + (wv * 32 + mt * 16 + lid) * 32 + quad * 8);
    #pragma unroll
    for (int nt = 0; nt < 8; ++nt)
      bfr[nt] = *(const bf16x8*)(Bt + (nt * 16 + lid) * 32 + quad * 8);
    #pragma unroll
    for (int mt = 0; mt < 2; ++mt)
      #pragma unroll
      for (int nt = 0; nt < 8; ++nt)
        acc[mt][nt] = __builtin_amdgcn_mfma_f32_16x16x32_bf16(af[mt], bfr[nt], acc[mt][nt], 0, 0, 0);
  }

  // C/D layout (m89-verified): col = lane&15, row = quad*4 + reg
  float mx[2][4], sm[2][4];
  #pragma unroll
  for (int mt = 0; mt < 2; ++mt)
    #pragma unroll
    for (int r = 0; r < 4; ++r) mx[mt][r] = -3.0e38f;
  #pragma unroll
  for (int mt = 0; mt < 2; ++mt)
    #pragma unroll
    for (int nt = 0; nt < 8; ++nt)
      #pragma unroll
      for (int r = 0; r < 4; ++r){
        const int mg = m0 + wv * 32 + mt * 16 + quad * 4 + r;
        const int ng = n0 + nt * 16 + lid;
        const float x = acc[mt][nt][r] * INV_T;
        outp[(size_t)mg * NCOLS + 1 + ng] = x;
        mx[mt][r] = fmaxf(mx[mt][r], x);
      }
  // 16-lane (lid) reduction: each quad owns its own 4 rows per mt
  #pragma unroll
  for (int mt = 0; mt < 2; ++mt)
    #pragma unroll
    for (int r = 0; r < 4; ++r){
      #pragma unroll
      for (int s = 8; s >= 1; s >>= 1)
        mx[mt][r] = fmaxf(mx[mt][r], __shfl_xor(mx[mt][r], s, 64));
      sm[mt][r] = 0.f;
    }
  #pragma unroll
  for (int mt = 0; mt < 2; ++mt)
    #pragma unroll
    for (int nt = 0; nt < 8; ++nt)
      #pragma unroll
      for (int r = 0; r < 4; ++r)
        sm[mt][r] += __expf(acc[mt][nt][r] * INV_T - mx[mt][r]);
  #pragma unroll
  for (int mt = 0; mt < 2; ++mt)
    #pragma unroll
    for (int r = 0; r < 4; ++r){
      #pragma unroll
      for (int s = 8; s >= 1; s >>= 1)
        sm[mt][r] += __shfl_xor(sm[mt][r], s, 64);
      if (lid == 0){
        const int mg = m0 + wv * 32 + mt * 16 + quad * 4 + r;
        pm[(size_t)mg * NBLK1 + blockIdx.y] = mx[mt][r];
        ps[(size_t)mg * NBLK1 + blockIdx.y] = sm[mt][r];
      }
    }
}

// ================== GEMM2: 256x256 tile, BK=64, 8 waves, FREE-RUN K-loop.
// ONE barrier + ONE vmcnt(0) per K-tile (seal-then-read): all 8 stage-loads
// for kt+1 are issued EARLY in kt, drained at the kt boundary when they are
// ~1500 cyc old (no latency stall). Inside the K-tile waves free-run with the
// fine interleave {MMQ; RD(next operand); MMQ; ...}; the last quadrant's MFMA
// slides past the barrier (register-only) so waves exit the barrier straight
// into MFMA work. This removes the 8-barrier/kt lockstep that serialized the
// MFMA / LDS / VALU pipes (measured: 31% + 26% + ~33% ~= 100% of 7050 cyc/kt).

static __device__ __forceinline__ void stage_half_g2_dummy(){}

#define RDA(mi_, SRC) do { _Pragma("unroll") for (int mf = 0; mf < 4; ++mf){ \
    const int R_ = (mi_) * 128 + wm * 64 + mf * 16 + lid; \
    av[mi_][mf][0] = *(const bf16x8*)((SRC) + R_ * 64 + sw0); \
    av[mi_][mf][1] = *(const bf16x8*)((SRC) + R_ * 64 + sw1); } } while(0)

#define RDB(nj_, SRC) do { _Pragma("unroll") for (int nf = 0; nf < 2; ++nf){ \
    const int S_ = (nj_) * 128 + wn * 32 + nf * 16 + lid; \
    bv[nj_][nf][0] = *(const bf16x8*)((SRC) + S_ * 64 + sw0); \
    bv[nj_][nf][1] = *(const bf16x8*)((SRC) + S_ * 64 + sw1); } } while(0)

#define MMQ(mi_, nj_) do { __builtin_amdgcn_s_setprio(1); \
    _Pragma("unroll") for (int mf = 0; mf < 4; ++mf) \
    _Pragma("unroll") for (int nf = 0; nf < 2; ++nf){ \
      acc[mi_][nj_][mf][nf] = __builtin_amdgcn_mfma_f32_16x16x32_bf16(av[mi_][mf][0], bv[nj_][nf][0], acc[mi_][nj_][mf][nf], 0, 0, 0); \
      acc[mi_][nj_][mf][nf] = __builtin_amdgcn_mfma_f32_16x16x32_bf16(av[mi_][mf][1], bv[nj_][nf][1], acc[mi_][nj_][mf][nf], 0, 0, 0); } \
    __builtin_amdgcn_s_setprio(0); } while(0)

// 2 async 16B loads per thread = one 128x64 bf16 half-tile across 512 threads.
// ro0/ro1 are per-thread invariant element offsets (row*DMLP + swizzled granule).
#define STAGE(base, kc, dst) do { \
  GLDS16((base) + ro0 + (kc), (dst) + t * 8); \
  GLDS16((base) + ro1 + (kc), (dst) + (512 + t) * 8); } while(0)

__global__ __launch_bounds__(512, 2) void gemm2_topk(
    const unsigned short* __restrict__ A, const unsigned short* __restrict__ BT,
    float* __restrict__ cval, int* __restrict__ cidx){
  // [buf][0=A,1=B][256 rows x 64 cols] bf16 = 128 KB total
  __shared__ __attribute__((aligned(16))) unsigned short lds[2][2][256 * 64];

  const int t    = threadIdx.x;           // 0..511
  const int lane = t & 63;
  const int wv   = t >> 6;                // wave 0..7
  const int wm   = wv >> 2;               // 0..1 (M within quadrant)
  const int wn   = wv & 3;                // 0..3 (N within quadrant)
  const int lid  = lane & 15;
  const int quad = lane >> 4;
  const int l7   = lid & 7;
  const int sw0  = ((quad    ) ^ l7) * 8; // swizzled granule offset, ks=0
  const int sw1  = ((quad ^ 4) ^ l7) * 8; // ks=1

  // T1: bijective XCD-chunked remap (1280 % 8 == 0): XCD x gets 32 consecutive
  // N-tiles x all 5 M-tiles -> the 5 sharers of each 1MB B-slab are co-resident.
  const int h  = blockIdx.x;
  const int wg = (h & 7) * 160 + (h >> 3);
  const int bm = wg % 5;
  const int bn = wg / 5;
  const int m0 = bm * 256;
  const int n0 = bn * 256;

  // per-thread invariant staging offsets (rule #21: source carries the swizzle)
  const int r0s = t >> 3,        r1s = (512 + t) >> 3;
  const int g0  = (t & 7) ^ (r0s & 7), g1 = (t & 7) ^ (r1s & 7);
  const int ro0 = r0s * DMLP + g0 * 8;
  const int ro1 = r1s * DMLP + g1 * 8;
  const unsigned short* aB0 = A  + (size_t)m0          * DMLP;
  const unsigned short* aB1 = A  + (size_t)(m0 + 128)  * DMLP;
  const unsigned short* bB0 = BT + (size_t)n0          * DMLP;
  const unsigned short* bB1 = BT + (size_t)(n0 + 128)  * DMLP;

  f32x4 acc[2][2][4][2];
  #pragma unroll
  for (int a = 0; a < 2; ++a)
    #pragma unroll
    for (int b = 0; b < 2; ++b)
      #pragma unroll
      for (int c = 0; c < 4; ++c)
        #pragma unroll
        for (int d = 0; d < 2; ++d)
          acc[a][b][c][d] = f32x4{0.f, 0.f, 0.f, 0.f};

  bf16x8 av[2][4][2];      // both A operand sets held across the K-tile
  bf16x8 bv[2][2][2];      // both B operand sets held across the K-tile

  // prologue: stage all 4 halves of kt0, seal, go
  STAGE(aB0, 0, &lds[0][0][0]);
  STAGE(bB0, 0, &lds[0][1][0]);
  STAGE(aB1, 0, &lds[0][0][128 * 64]);
  STAGE(bB1, 0, &lds[0][1][128 * 64]);
  VMW(0);
  BAR();

  #pragma unroll 2
  for (int kt = 0; kt < NTK; ++kt){
    unsigned short* curA = &lds[kt & 1][0][0];
    unsigned short* curB = &lds[kt & 1][1][0];
    unsigned short* nxtA = &lds[(kt + 1) & 1][0][0];
    unsigned short* nxtB = &lds[(kt + 1) & 1][1][0];

    // deferred last quadrant of kt-1 (register-only: legal past the barrier)
    if (kt) MMQ(0, 1);

    RDA(0, curA);                       // av[0] <- A0(kt)
    RDB(0, curB);                       // bv[0] <- B0(kt)

    if (kt + 1 < NTK){                  // issue-early: all 8 loads for kt+1
      const int kc = (kt + 1) * 64;
      STAGE(aB0, kc, nxtA);
      STAGE(bB0, kc, nxtB);
      STAGE(aB1, kc, nxtA + 128 * 64);
      STAGE(bB1, kc, nxtB + 128 * 64);
    }

    MMQ(0, 0);                          // overlaps RDA(1) issue below
    RDA(1, curA);                       // av[1] <- A1(kt)
    MMQ(1, 0);
    RDB(1, curB);                       // bv[1] <- B1(kt)
    MMQ(1, 1);

    VMW(0);                             // drain kt+1 stages (issued ~1500cy ago)
    BAR();                              // seal: next kt may read nxt buffers
  }
  MMQ(0, 1);                            // last K-tile's deferred quadrant

  // ---- fused top-5 over this block's 256 cols (chunk = bn) ----
  float* scratch = (float*)&lds[0][0][0];   // 128 x 133 f32 = 68 KB
  const int erow = t >> 2;     // 0..127 (row within half)
  const int eh   = t & 3;      // 4 threads/row, interleaved cols (bank-friendly)
  #pragma unroll
  for (int mi = 0; mi < 2; ++mi){
    float v[5]; int ix[5];
    #pragma unroll
    for (int j = 0; j < 5; ++j){ v[j] = -3.0e38f; ix[j] = 0; }
    #pragma unroll
    for (int nj = 0; nj < 2; ++nj){
      __syncthreads();
      #pragma unroll
      for (int mf = 0; mf < 4; ++mf)
        #pragma unroll
        for (int nf = 0; nf < 2; ++nf)
          #pragma unroll
          for (int r = 0; r < 4; ++r)
            scratch[(wm * 64 + mf * 16 + quad * 4 + r) * 133 + wn * 32 + nf * 16 + lid]
              = acc[mi][nj][mf][nf][r];
      __syncthreads();
      for (int j = 0; j < 32; ++j)
        tk_insert(v, ix, scratch[erow * 133 + j * 4 + eh], n0 + nj * 128 + j * 4 + eh);
    }
    #pragma unroll
    for (int s = 1; s <= 2; s <<= 1){      // merge the 4 per-row lists
      float pv[5]; int pi[5];
      #pragma unroll
      for (int j = 0; j < 5; ++j){ pv[j] = __shfl_xor(v[j], s, 64); pi[j] = __shfl_xor(ix[j], s, 64); }
      #pragma unroll
      for (int j = 0; j < 5; ++j) tk_insert(v, ix, pv[j], pi[j]);
    }
    if (eh == 0){
      const int rowg = m0 + mi * 128 + erow;
      const size_t cb = ((size_t)rowg * NCHUNK + bn) * NTOPK;
      #pragma unroll
      for (int j = 0; j < 5; ++j){ cval[cb + j] = v[j]; cidx[cb + j] = ix[j]; }
    }
  }
}

// ---------- merge 256 chunk top-5 lists per row -> global top-5 indices
__global__ __launch_bounds__(256) void topk_merge(
    const float* __restrict__ cval, const int* __restrict__ cidx, int* __restrict__ knn){
  const int row = blockIdx.x, t = threadIdx.x;
  float v[5]; int ix[5];
  #pragma unroll
  for (int j = 0; j < 5; ++j){ v[j] = -3.0e38f; ix[j] = 0; }
  const size_t base = (size_t)row * (NCHUNK * NTOPK);
  #pragma unroll
  for (int j = 0; j < 5; ++j){                   // 1280 candidates / 256 threads
    const int c = t * 5 + j;
    tk_insert(v, ix, cval[base + c], cidx[base + c]);
  }
  __shared__ float lv[256 * 5];
  __shared__ int   li[256 * 5];
  #pragma unroll
  for (int j = 0; j < 5; ++j){ lv[t * 5 + j] = v[j]; li[t * 5 + j] = ix[j]; }
  __syncthreads();
  if (t < 64){
    float v2[5]; int ix2[5];
    #pragma unroll
    for (int j = 0; j < 5; ++j){ v2[j] = -3.0e38f; ix2[j] = 0; }
    for (int L = 0; L < 4; ++L)
      #pragma unroll
      for (int j = 0; j < 5; ++j)
        tk_insert(v2, ix2, lv[(t * 4 + L) * 5 + j], li[(t * 4 + L) * 5 + j]);
    #pragma unroll
    for (int s = 32; s >= 1; s >>= 1){           // tree merge; lane 0 ends valid
      float pv[5]; int pi[5];
      #pragma unroll
      for (int j = 0; j < 5; ++j){ pv[j] = __shfl_down(v2[j], s, 64); pi[j] = __shfl_down(ix2[j], s, 64); }
      #pragma unroll
      for (int j = 0; j < 5; ++j) tk_insert(v2, ix2, pv[j], pi[j]);
    }
    if (t == 0){
      #pragma unroll
      for (int j = 0; j < 5; ++j) knn[(size_t)row * NTOPK + j] = ix2[j];
    }
  }
}

// ---------- merge per-tile lse partials -> per-row logsumexp
__global__ __launch_bounds__(256) void lse_merge(
    const float* __restrict__ pm, const float* __restrict__ ps,
    float* __restrict__ lse){
  const int row = blockIdx.x, t = threadIdx.x;
  const float* pmr = pm + (size_t)row * NBLK1;
  const float* psr = ps + (size_t)row * NBLK1;
  float m = -1.0e30f, s = 0.f;
  #pragma unroll
  for (int c = 0; c < 2; ++c){               // 512 partials / 256 threads
    const float om = pmr[t + c * 256], os = psr[t + c * 256];
    const float nm = fmaxf(m, om);
    s = s * __expf(m - nm) + os * __expf(om - nm);
    m = nm;
  }
  #pragma unroll
  for (int sh = 32; sh >= 1; sh >>= 1){
    const float om = __shfl_down(m, sh, 64), os = __shfl_down(s, sh, 64);
    const float nm = fmaxf(m, om);
    s = s * __expf(m - nm) + os * __expf(om - nm);
    m = nm;
  }
  __shared__ float sm2[4], ss2[4];
  if ((t & 63) == 0){ sm2[t >> 6] = m; ss2[t >> 6] = s; }
  __syncthreads();
  if (t == 0){
    float M = sm2[0], S = ss2[0];
    #pragma unroll
    for (int w = 1; w < 4; ++w){
      const float nm = fmaxf(M, sm2[w]);
      S = S * __expf(M - nm) + ss2[w] * __expf(sm2[w] - nm);
      M = nm;
    }
    lse[row] = M + __logf(S);
  }
}

// ---------- loss = mean over 6400 of (lse[row] - logit[row][1+idx])
__global__ __launch_bounds__(256) void loss_kernel(
    const float* __restrict__ logits, const float* __restrict__ lse,
    const int* __restrict__ knn, float* __restrict__ loss){
  const int i = blockIdx.x * 256 + threadIdx.x;
  float c = 0.f;
  if (i < M_){
    const float l = lse[i];
    #pragma unroll
    for (int j = 0; j < 5; ++j){
      const int id = knn[(size_t)i * NTOPK + j];
      c += l - logits[(size_t)i * NCOLS + 1 + id];
    }
    c *= (1.0f / 6400.0f);
  }
  #pragma unroll
  for (int s = 32; s >= 1; s >>= 1) c += __shfl_down(c, s, 64);
  if ((threadIdx.x & 63) == 0) atomicAdd(loss, c);
}

extern "C" void kernel_launch(void* const* d_in, const int* in_sizes, int n_in,
                              void* d_out, int out_size, void* d_ws, size_t ws_size,
                              hipStream_t stream){
  const float* q   = (const float*)d_in[0];   // [256,5,128]
  const float* k   = (const float*)d_in[1];   // [256,128]
  const float* qbI = (const float*)d_in[2];   // [256,5,2048]
  const float* que = (const float*)d_in[3];   // [128,65536]
  const float* qbb = (const float*)d_in[4];   // [2048,65536]
  float* out = (float*)d_out;

  unsigned char* w = (unsigned char*)d_ws;
  unsigned short* qn   = (unsigned short*)w; w += (size_t)M_ * DIM  * 2;   // 320 KB
  unsigned short* qbn  = (unsigned short*)w; w += (size_t)M_ * DMLP * 2;   // 5 MB
  unsigned short* queT = (unsigned short*)w; w += (size_t)KQ * DIM  * 2;   // 16 MB
  unsigned short* qbbT = (unsigned short*)w; w += (size_t)KQ * DMLP * 2;   // 256 MB
  float* cval = (float*)w;                   w += (size_t)M_ * NCHUNK * NTOPK * 4;  // 6.5 MB
  int*   cidx = (int*)w;                     w += (size_t)M_ * NCHUNK * NTOPK * 4;  // 6.5 MB
  int*   knn  = (int*)w;                     w += (size_t)M_ * NTOPK * 4;
  float* lseb = (float*)w;                   w += (size_t)M_ * 4;
  float* pm   = (float*)w;                   w += (size_t)M_ * NBLK1 * 4;  // 2.6 MB
  float* ps   = (float*)w;                   w += (size_t)M_ * NBLK1 * 4;  // 2.6 MB

  // labels (1280 int32 zeros) + loss slot, contiguous after logits
  hipMemsetAsync(out + (size_t)M_ * NCOLS, 0, (M_ + 1) * sizeof(float), stream);

  transpose_bf16<<<dim3(KQ / 64, DIM  / 64), 256, 0, stream>>>(que, queT, DIM,  KQ);
  transpose_bf16<<<dim3(KQ / 64, DMLP / 64), 256, 0, stream>>>(qbb, qbbT, DMLP, KQ);
  normq_kernel <<<M_, 128, 0, stream>>>(q, k, qn, out);
  normqb_kernel<<<M_, 256, 0, stream>>>(qbI, qbn);
  // GEMM1: x = M-tiles (fast) so the 10 blocks sharing a B tile are adjacent
  gemm1_mfma<<<dim3(10, NBLK1), 256, 0, stream>>>(qn, queT, out, pm, ps);
  // GEMM2: 256^2 free-run K-loop (1 barrier/kt), 1280 blocks, XCD-chunked
  gemm2_topk<<<dim3(1280), 512, 0, stream>>>(qbn, qbbT, cval, cidx);
  topk_merge<<<M_, 256, 0, stream>>>(cval, cidx, knn);
  lse_merge<<<M_, 256, 0, stream>>>(pm, ps, lseb);
  loss_kernel<<<(M_ + 255) / 256, 256, 0, stream>>>(out, lseb, knn,
                                                    out + (size_t)M_ * NCOLS + M_);
}